// Round 1
// baseline (258.951 us; speedup 1.0000x reference)
//
#include <hip/hip_runtime.h>
#include <hip/hip_bf16.h>
#include <cstdint>

#define NDIM 128
#define KCLAMP 10.0f

__device__ __forceinline__ uint16_t f2bf(float f) {
    uint32_t u = __float_as_uint(f);
    uint32_t r = (u + 0x7fffu + ((u >> 16) & 1u)) >> 16;   // RNE
    return (uint16_t)r;
}
__device__ __forceinline__ float bf_lo(uint32_t v) { return __uint_as_float(v << 16); }
__device__ __forceinline__ float bf_hi(uint32_t v) { return __uint_as_float(v & 0xffff0000u); }

// feat[r][c] = h[r][c] * rsqrt(max(out_deg[r],1)), bf16
__global__ void k_feat(const float* __restrict__ h, const int* __restrict__ odeg,
                       uint16_t* __restrict__ feat, int nsrc) {
    int idx = blockIdx.x * blockDim.x + threadIdx.x;   // one float4 per thread
    int total = nsrc * (NDIM / 4);
    if (idx >= total) return;
    int row = idx >> 5;                                // NDIM/4 = 32
    float dg = (float)odeg[row];
    float nrm = rsqrtf(fmaxf(dg, 1.0f));
    float4 v = ((const float4*)h)[idx];
    ushort4 o;
    o.x = f2bf(v.x * nrm);
    o.y = f2bf(v.y * nrm);
    o.z = f2bf(v.z * nrm);
    o.w = f2bf(v.w * nrm);
    ((ushort4*)feat)[idx] = o;
}

// row_start[d] = lower_bound(sdst, d); sdst sorted ascending
__global__ void k_rowptr(const int* __restrict__ sdst, int E,
                         int* __restrict__ row_start, int ndst) {
    int d = blockIdx.x * blockDim.x + threadIdx.x;
    if (d > ndst) return;
    int lo = 0, hi = E;
    while (lo < hi) {
        int mid = (lo + hi) >> 1;
        if (sdst[mid] < d) lo = mid + 1; else hi = mid;
    }
    row_start[d] = lo;
}

// one wave per dst: agg[d][:] = sum_{i in segment} feat[src[i]][:]
__global__ void k_agg(const uint16_t* __restrict__ feat,
                      const float* __restrict__ h, const int* __restrict__ odeg,
                      const int* __restrict__ ssrc, const int* __restrict__ row_start,
                      float* __restrict__ agg, int ndst, int use_feat) {
    int gtid = blockIdx.x * blockDim.x + threadIdx.x;
    int wave = gtid >> 6;
    int lane = threadIdx.x & 63;
    int nwaves = (gridDim.x * blockDim.x) >> 6;
    for (int d = wave; d < ndst; d += nwaves) {
        int s = row_start[d], e = row_start[d + 1];
        float a0 = 0.f, a1 = 0.f;
        if (use_feat) {
            int i = s;
            for (; i + 1 < e; i += 2) {
                int s0 = ssrc[i], s1 = ssrc[i + 1];
                uint32_t v0 = *(const uint32_t*)(feat + (size_t)s0 * NDIM + lane * 2);
                uint32_t v1 = *(const uint32_t*)(feat + (size_t)s1 * NDIM + lane * 2);
                a0 += bf_lo(v0) + bf_lo(v1);
                a1 += bf_hi(v0) + bf_hi(v1);
            }
            if (i < e) {
                int s0 = ssrc[i];
                uint32_t v0 = *(const uint32_t*)(feat + (size_t)s0 * NDIM + lane * 2);
                a0 += bf_lo(v0);
                a1 += bf_hi(v0);
            }
        } else {
            for (int i = s; i < e; i++) {
                int s0 = ssrc[i];
                float dg = (float)odeg[s0];
                float nrm = rsqrtf(fmaxf(dg, 1.0f));
                float2 v = ((const float2*)h)[(size_t)s0 * (NDIM / 2) + lane];
                a0 += v.x * nrm;
                a1 += v.y * nrm;
            }
        }
        float2 o; o.x = a0; o.y = a1;
        ((float2*)agg)[(size_t)d * (NDIM / 2) + lane] = o;
    }
}

// in-place: io rows = agg -> rst = (agg @ W) * rsqrt(clamp(in_deg,1,K)) + bias
// block: 64 rows x 128 cols, 256 threads, each thread 8 rows x 4 cols.
__global__ __launch_bounds__(256) void k_gemm(float* __restrict__ io,
                                              const float* __restrict__ W,
                                              const float* __restrict__ bias,
                                              const int* __restrict__ ideg, int M) {
    __shared__ float Ws[NDIM][NDIM];   // 64 KB
    int tx = threadIdx.x;
    {
        const float4* Wv = (const float4*)W;
        float4* Wsv = (float4*)&Ws[0][0];
        for (int i = tx; i < NDIM * NDIM / 4; i += 256) Wsv[i] = Wv[i];
    }
    __syncthreads();

    int cg = tx & 31;          // col group -> cols 4*cg..4*cg+3
    int rg = tx >> 5;          // row group -> 8 rows
    int r0 = blockIdx.x * 64 + rg * 8;
    int c0 = cg * 4;

    float acc[8][4];
#pragma unroll
    for (int r = 0; r < 8; ++r)
#pragma unroll
        for (int c = 0; c < 4; ++c) acc[r][c] = 0.f;

    for (int k4 = 0; k4 < NDIM / 4; ++k4) {
        float4 wk0 = *(const float4*)&Ws[4 * k4 + 0][c0];
        float4 wk1 = *(const float4*)&Ws[4 * k4 + 1][c0];
        float4 wk2 = *(const float4*)&Ws[4 * k4 + 2][c0];
        float4 wk3 = *(const float4*)&Ws[4 * k4 + 3][c0];
#pragma unroll
        for (int r = 0; r < 8; ++r) {
            int row = r0 + r;
            if (row < M) {
                float4 a = ((const float4*)io)[(size_t)row * (NDIM / 4) + k4];
                acc[r][0] += a.x * wk0.x + a.y * wk1.x + a.z * wk2.x + a.w * wk3.x;
                acc[r][1] += a.x * wk0.y + a.y * wk1.y + a.z * wk2.y + a.w * wk3.y;
                acc[r][2] += a.x * wk0.z + a.y * wk1.z + a.z * wk2.z + a.w * wk3.z;
                acc[r][3] += a.x * wk0.w + a.y * wk1.w + a.z * wk2.w + a.w * wk3.w;
            }
        }
    }
    __syncthreads();   // all reads of this block's rows complete before in-place writes

    float4 b = *(const float4*)&bias[c0];
#pragma unroll
    for (int r = 0; r < 8; ++r) {
        int row = r0 + r;
        if (row < M) {
            float dg = (float)ideg[row];
            float nrm = rsqrtf(fminf(fmaxf(dg, 1.0f), KCLAMP));
            float4 o;
            o.x = acc[r][0] * nrm + b.x;
            o.y = acc[r][1] * nrm + b.y;
            o.z = acc[r][2] * nrm + b.z;
            o.w = acc[r][3] * nrm + b.w;
            ((float4*)io)[(size_t)row * (NDIM / 4) + cg] = o;
        }
    }
}

extern "C" void kernel_launch(void* const* d_in, const int* in_sizes, int n_in,
                              void* d_out, int out_size, void* d_ws, size_t ws_size,
                              hipStream_t stream) {
    const float* h_src  = (const float*)d_in[0];
    const float* weight = (const float*)d_in[1];
    const float* bias   = (const float*)d_in[2];
    const int*   ssrc   = (const int*)d_in[3];
    const int*   sdst   = (const int*)d_in[4];
    const int*   odeg   = (const int*)d_in[5];
    const int*   ideg   = (const int*)d_in[6];
    float* out = (float*)d_out;

    int E    = in_sizes[3];
    int nsrc = in_sizes[0] / NDIM;
    int ndst = out_size / NDIM;

    int* row_start = (int*)d_ws;
    size_t feat_off = (size_t)4 << 20;                    // 4 MB
    uint16_t* feat = (uint16_t*)((char*)d_ws + feat_off);
    size_t need = feat_off + (size_t)nsrc * NDIM * 2;
    int use_feat = (ws_size >= need) ? 1 : 0;

    if (use_feat) {
        int total = nsrc * (NDIM / 4);
        k_feat<<<(total + 255) / 256, 256, 0, stream>>>(h_src, odeg, feat, nsrc);
    }
    k_rowptr<<<(ndst + 1 + 255) / 256, 256, 0, stream>>>(sdst, E, row_start, ndst);
    k_agg<<<2048, 256, 0, stream>>>(feat, h_src, odeg, ssrc, row_start, out, ndst, use_feat);
    k_gemm<<<(ndst + 63) / 64, 256, 0, stream>>>(out, weight, bias, ideg, ndst);
}

// Round 2
// 107.514 us; speedup vs baseline: 2.4085x; 2.4085x over previous
//
#include <hip/hip_runtime.h>
#include <hip/hip_bf16.h>
#include <cstdint>

#define NDIM 128
#define KCLAMP 10.0f

using bf16x8 = __attribute__((ext_vector_type(8))) short;
using f32x4  = __attribute__((ext_vector_type(4))) float;

__device__ __forceinline__ uint16_t f2bf(float f) {
    uint32_t u = __float_as_uint(f);
    uint32_t r = (u + 0x7fffu + ((u >> 16) & 1u)) >> 16;   // RNE
    return (uint16_t)r;
}
__device__ __forceinline__ float bf_lo(uint32_t v) { return __uint_as_float(v << 16); }
__device__ __forceinline__ float bf_hi(uint32_t v) { return __uint_as_float(v & 0xffff0000u); }

// feat[r][c] = h[r][c] * rsqrt(max(out_deg[r],1)), bf16
__global__ void k_feat(const float* __restrict__ h, const int* __restrict__ odeg,
                       uint16_t* __restrict__ feat, int nsrc) {
    int idx = blockIdx.x * blockDim.x + threadIdx.x;   // one float4 per thread
    int total = nsrc * (NDIM / 4);
    if (idx >= total) return;
    int row = idx >> 5;                                // NDIM/4 = 32
    float dg = (float)odeg[row];
    float nrm = rsqrtf(fmaxf(dg, 1.0f));
    float4 v = ((const float4*)h)[idx];
    ushort4 o;
    o.x = f2bf(v.x * nrm);
    o.y = f2bf(v.y * nrm);
    o.z = f2bf(v.z * nrm);
    o.w = f2bf(v.w * nrm);
    ((ushort4*)feat)[idx] = o;
}

// row_start[d] = lower_bound(sdst, d)
__global__ void k_rowptr(const int* __restrict__ sdst, int E,
                         int* __restrict__ row_start, int ndst) {
    int d = blockIdx.x * blockDim.x + threadIdx.x;
    if (d > ndst) return;
    int lo = 0, hi = E;
    while (lo < hi) {
        int mid = (lo + hi) >> 1;
        if (sdst[mid] < d) lo = mid + 1; else hi = mid;
    }
    row_start[d] = lo;
}

// one wave per dst: agg[d][:] = sum feat[src[i]][:], written as bf16 [d][128]
__global__ void k_agg_bf(const uint16_t* __restrict__ feat,
                         const int* __restrict__ ssrc, const int* __restrict__ row_start,
                         uint32_t* __restrict__ agg, int ndst) {
    int gtid = blockIdx.x * blockDim.x + threadIdx.x;
    int wave = gtid >> 6;
    int lane = threadIdx.x & 63;
    int nwaves = (gridDim.x * blockDim.x) >> 6;
    for (int d = wave; d < ndst; d += nwaves) {
        int s = row_start[d], e = row_start[d + 1];
        float a0 = 0.f, a1 = 0.f;
        int i = s;
        for (; i + 1 < e; i += 2) {
            int s0 = ssrc[i], s1 = ssrc[i + 1];
            uint32_t v0 = *(const uint32_t*)(feat + (size_t)s0 * NDIM + lane * 2);
            uint32_t v1 = *(const uint32_t*)(feat + (size_t)s1 * NDIM + lane * 2);
            a0 += bf_lo(v0) + bf_lo(v1);
            a1 += bf_hi(v0) + bf_hi(v1);
        }
        if (i < e) {
            uint32_t v0 = *(const uint32_t*)(feat + (size_t)ssrc[i] * NDIM + lane * 2);
            a0 += bf_lo(v0);
            a1 += bf_hi(v0);
        }
        agg[(size_t)d * (NDIM / 2) + lane] = (uint32_t)f2bf(a0) | ((uint32_t)f2bf(a1) << 16);
    }
}

// fallback f32 agg into out (if workspace too small)
__global__ void k_agg_f32(const uint16_t* __restrict__ feat,
                          const float* __restrict__ h, const int* __restrict__ odeg,
                          const int* __restrict__ ssrc, const int* __restrict__ row_start,
                          float* __restrict__ agg, int ndst, int use_feat) {
    int gtid = blockIdx.x * blockDim.x + threadIdx.x;
    int wave = gtid >> 6;
    int lane = threadIdx.x & 63;
    int nwaves = (gridDim.x * blockDim.x) >> 6;
    for (int d = wave; d < ndst; d += nwaves) {
        int s = row_start[d], e = row_start[d + 1];
        float a0 = 0.f, a1 = 0.f;
        if (use_feat) {
            for (int i = s; i < e; i++) {
                uint32_t v0 = *(const uint32_t*)(feat + (size_t)ssrc[i] * NDIM + lane * 2);
                a0 += bf_lo(v0);
                a1 += bf_hi(v0);
            }
        } else {
            for (int i = s; i < e; i++) {
                int s0 = ssrc[i];
                float nrm = rsqrtf(fmaxf((float)odeg[s0], 1.0f));
                float2 v = ((const float2*)h)[(size_t)s0 * (NDIM / 2) + lane];
                a0 += v.x * nrm;
                a1 += v.y * nrm;
            }
        }
        float2 o; o.x = a0; o.y = a1;
        ((float2*)agg)[(size_t)d * (NDIM / 2) + lane] = o;
    }
}

// one-time: fragment W into MFMA B-layout (bf16).
// wfrag[((n*4+s)*64+lane)*8+i] = bf16(W[k][col]),  k=s*32+8*(lane>>4)+i, col=n*16+(lane&15)
__global__ void k_wfrag(const float* __restrict__ W, uint16_t* __restrict__ wfrag) {
    int t = blockIdx.x * blockDim.x + threadIdx.x;
    if (t >= NDIM * NDIM) return;
    int i    = t & 7;
    int lane = (t >> 3) & 63;
    int s    = (t >> 9) & 3;
    int n    = t >> 11;
    int k    = s * 32 + 8 * (lane >> 4) + i;
    int col  = n * 16 + (lane & 15);
    wfrag[t] = f2bf(W[k * NDIM + col]);
}

// MFMA GEMM: out[M][128] = (A_bf16[M][128] @ W) * rsqrt(clamp(ideg,1,K)) + bias
// block = 256 thr = 4 waves; wave w owns rows blk*64 + w*16 .. +15
__global__ __launch_bounds__(256) void k_gemm_mfma(const uint16_t* __restrict__ A,
                                                   const uint16_t* __restrict__ wfrag,
                                                   const float* __restrict__ bias,
                                                   const int* __restrict__ ideg,
                                                   float* __restrict__ out, int M) {
    __shared__ uint16_t Ws[NDIM * NDIM];   // 32 KB, fragment layout
    int tx = threadIdx.x;
    for (int i = tx; i < NDIM * NDIM / 8; i += 256)
        ((int4*)Ws)[i] = ((const int4*)wfrag)[i];
    __syncthreads();

    int wave = tx >> 6, lane = tx & 63;
    int r0 = blockIdx.x * 64 + wave * 16;
    int arow = r0 + (lane & 15);
    if (arow >= M) arow = M - 1;            // clamp loads; stores predicated
    const bf16x8* Arow = (const bf16x8*)(A + (size_t)arow * NDIM);
    int g = lane >> 4;

    f32x4 acc[8];
#pragma unroll
    for (int n = 0; n < 8; ++n) acc[n] = (f32x4){0.f, 0.f, 0.f, 0.f};

#pragma unroll
    for (int s = 0; s < 4; ++s) {
        bf16x8 af = Arow[s * 4 + g];        // k = s*32 + 8g .. +7
#pragma unroll
        for (int n = 0; n < 8; ++n) {
            bf16x8 bfr = *(const bf16x8*)(Ws + (((n * 4 + s) * 64 + lane) << 3));
            acc[n] = __builtin_amdgcn_mfma_f32_16x16x32_bf16(af, bfr, acc[n], 0, 0, 0);
        }
    }

    int col = lane & 15;
    float nrm[4];
    int rowbase = r0 + g * 4;
#pragma unroll
    for (int r = 0; r < 4; ++r) {
        int row = rowbase + r;
        nrm[r] = (row < M) ? rsqrtf(fminf(fmaxf((float)ideg[row], 1.0f), KCLAMP)) : 0.f;
    }
#pragma unroll
    for (int n = 0; n < 8; ++n) {
        float b = bias[n * 16 + col];
#pragma unroll
        for (int r = 0; r < 4; ++r) {
            int row = rowbase + r;
            if (row < M)
                out[(size_t)row * NDIM + n * 16 + col] = acc[n][r] * nrm[r] + b;
        }
    }
}

// fallback f32 GEMM (round-1 version, in-place on out)
__global__ __launch_bounds__(256) void k_gemm_f32(float* __restrict__ io,
                                                  const float* __restrict__ W,
                                                  const float* __restrict__ bias,
                                                  const int* __restrict__ ideg, int M) {
    __shared__ float Wsf[NDIM][NDIM];
    int tx = threadIdx.x;
    {
        const float4* Wv = (const float4*)W;
        float4* Wsv = (float4*)&Wsf[0][0];
        for (int i = tx; i < NDIM * NDIM / 4; i += 256) Wsv[i] = Wv[i];
    }
    __syncthreads();
    int cg = tx & 31, rg = tx >> 5;
    int r0 = blockIdx.x * 64 + rg * 8, c0 = cg * 4;
    float acc[8][4];
#pragma unroll
    for (int r = 0; r < 8; ++r)
#pragma unroll
        for (int c = 0; c < 4; ++c) acc[r][c] = 0.f;
    for (int k4 = 0; k4 < NDIM / 4; ++k4) {
        float4 wk0 = *(const float4*)&Wsf[4 * k4 + 0][c0];
        float4 wk1 = *(const float4*)&Wsf[4 * k4 + 1][c0];
        float4 wk2 = *(const float4*)&Wsf[4 * k4 + 2][c0];
        float4 wk3 = *(const float4*)&Wsf[4 * k4 + 3][c0];
#pragma unroll
        for (int r = 0; r < 8; ++r) {
            int row = r0 + r;
            if (row < M) {
                float4 a = ((const float4*)io)[(size_t)row * (NDIM / 4) + k4];
                acc[r][0] += a.x * wk0.x + a.y * wk1.x + a.z * wk2.x + a.w * wk3.x;
                acc[r][1] += a.x * wk0.y + a.y * wk1.y + a.z * wk2.y + a.w * wk3.y;
                acc[r][2] += a.x * wk0.z + a.y * wk1.z + a.z * wk2.z + a.w * wk3.z;
                acc[r][3] += a.x * wk0.w + a.y * wk1.w + a.z * wk2.w + a.w * wk3.w;
            }
        }
    }
    __syncthreads();
    float4 b = *(const float4*)&bias[c0];
#pragma unroll
    for (int r = 0; r < 8; ++r) {
        int row = r0 + r;
        if (row < M) {
            float nrm = rsqrtf(fminf(fmaxf((float)ideg[row], 1.0f), KCLAMP));
            float4 o;
            o.x = acc[r][0] * nrm + b.x;
            o.y = acc[r][1] * nrm + b.y;
            o.z = acc[r][2] * nrm + b.z;
            o.w = acc[r][3] * nrm + b.w;
            ((float4*)io)[(size_t)row * (NDIM / 4) + cg] = o;
        }
    }
}

extern "C" void kernel_launch(void* const* d_in, const int* in_sizes, int n_in,
                              void* d_out, int out_size, void* d_ws, size_t ws_size,
                              hipStream_t stream) {
    const float* h_src  = (const float*)d_in[0];
    const float* weight = (const float*)d_in[1];
    const float* bias   = (const float*)d_in[2];
    const int*   ssrc   = (const int*)d_in[3];
    const int*   sdst   = (const int*)d_in[4];
    const int*   odeg   = (const int*)d_in[5];
    const int*   ideg   = (const int*)d_in[6];
    float* out = (float*)d_out;

    int E    = in_sizes[3];
    int nsrc = in_sizes[0] / NDIM;
    int ndst = out_size / NDIM;

    size_t featB = (size_t)nsrc * NDIM * 2;
    size_t aggB  = (size_t)ndst * NDIM * 2;

    // layout: [0,1MB) row_start ; [1MB, 1MB+32KB) wfrag ; [2MB, ..) feat ; then agg
    int*      row_start = (int*)d_ws;
    uint16_t* wfrag = (uint16_t*)((char*)d_ws + ((size_t)1 << 20));
    size_t feat_off = (size_t)2 << 20;
    uint16_t* feat  = (uint16_t*)((char*)d_ws + feat_off);
    size_t agg_off  = feat_off + ((featB + 255) & ~(size_t)255);
    uint32_t* aggbf = (uint32_t*)((char*)d_ws + agg_off);
    size_t need_full = agg_off + aggB;
    size_t need_feat = feat_off + featB;

    k_rowptr<<<(ndst + 1 + 255) / 256, 256, 0, stream>>>(sdst, E, row_start, ndst);

    if (ws_size >= need_full) {
        // fast path: bf16 agg + MFMA GEMM
        k_wfrag<<<(NDIM * NDIM + 255) / 256, 256, 0, stream>>>(weight, wfrag);
        int total = nsrc * (NDIM / 4);
        k_feat<<<(total + 255) / 256, 256, 0, stream>>>(h_src, odeg, feat, nsrc);
        k_agg_bf<<<2048, 256, 0, stream>>>(feat, ssrc, row_start, aggbf, ndst);
        k_gemm_mfma<<<(ndst + 63) / 64, 256, 0, stream>>>((const uint16_t*)aggbf, wfrag,
                                                          bias, ideg, out, ndst);
    } else {
        int use_feat = (ws_size >= need_feat) ? 1 : 0;
        if (use_feat) {
            int total = nsrc * (NDIM / 4);
            k_feat<<<(total + 255) / 256, 256, 0, stream>>>(h_src, odeg, feat, nsrc);
        }
        k_agg_f32<<<2048, 256, 0, stream>>>(feat, h_src, odeg, ssrc, row_start, out, ndst, use_feat);
        k_gemm_f32<<<(ndst + 63) / 64, 256, 0, stream>>>(out, weight, bias, ideg, ndst);
    }
}

// Round 3
// 89.068 us; speedup vs baseline: 2.9073x; 1.2071x over previous
//
#include <hip/hip_runtime.h>
#include <hip/hip_bf16.h>
#include <cstdint>

#define NDIM 128
#define KCLAMP 10.0f

using bf16x8 = __attribute__((ext_vector_type(8))) short;
using f32x4  = __attribute__((ext_vector_type(4))) float;

__device__ __forceinline__ uint16_t f2bf(float f) {
    uint32_t u = __float_as_uint(f);
    uint32_t r = (u + 0x7fffu + ((u >> 16) & 1u)) >> 16;   // RNE
    return (uint16_t)r;
}
__device__ __forceinline__ float bf_lo(uint32_t v) { return __uint_as_float(v << 16); }
__device__ __forceinline__ float bf_hi(uint32_t v) { return __uint_as_float(v & 0xffff0000u); }

// feat[r][c] = h[r][c] * rsqrt(max(out_deg[r],1)), bf16
__global__ void k_feat(const float* __restrict__ h, const int* __restrict__ odeg,
                       uint16_t* __restrict__ feat, int nsrc) {
    int idx = blockIdx.x * blockDim.x + threadIdx.x;   // one float4 per thread
    int total = nsrc * (NDIM / 4);
    if (idx >= total) return;
    int row = idx >> 5;                                // NDIM/4 = 32
    float dg = (float)odeg[row];
    float nrm = rsqrtf(fmaxf(dg, 1.0f));
    float4 v = ((const float4*)h)[idx];
    ushort4 o;
    o.x = f2bf(v.x * nrm);
    o.y = f2bf(v.y * nrm);
    o.z = f2bf(v.z * nrm);
    o.w = f2bf(v.w * nrm);
    ((ushort4*)feat)[idx] = o;
}

// row_start[d] = lower_bound(sdst, d)
__global__ void k_rowptr(const int* __restrict__ sdst, int E,
                         int* __restrict__ row_start, int ndst) {
    int d = blockIdx.x * blockDim.x + threadIdx.x;
    if (d > ndst) return;
    int lo = 0, hi = E;
    while (lo < hi) {
        int mid = (lo + hi) >> 1;
        if (sdst[mid] < d) lo = mid + 1; else hi = mid;
    }
    row_start[d] = lo;
}

// one wave per dst; 16 lanes per row (16B/lane), 4 edges per wave-instruction,
// unrolled 2x -> 8 edges (2 KB) in flight per wave.
__global__ void k_agg_bf(const uint16_t* __restrict__ feat,
                         const int* __restrict__ ssrc, const int* __restrict__ row_start,
                         uint16_t* __restrict__ agg, int ndst) {
    int gtid = blockIdx.x * blockDim.x + threadIdx.x;
    int wave = gtid >> 6;
    int lane = threadIdx.x & 63;
    int sub  = lane >> 4;          // edge slot 0..3
    int li   = lane & 15;          // 16B chunk within row
    int nwaves = (gridDim.x * blockDim.x) >> 6;

    for (int d = wave; d < ndst; d += nwaves) {
        int s = row_start[d], e = row_start[d + 1];
        float acc[8];
#pragma unroll
        for (int k = 0; k < 8; ++k) acc[k] = 0.f;

        int base = s;
        for (; base + 8 <= e; base += 8) {
            int i0 = base + sub;
            int i1 = base + 4 + sub;
            int s0 = ssrc[i0];
            int s1 = ssrc[i1];
            uint4 v0 = *(const uint4*)(feat + (size_t)s0 * NDIM + li * 8);
            uint4 v1 = *(const uint4*)(feat + (size_t)s1 * NDIM + li * 8);
            acc[0] += bf_lo(v0.x) + bf_lo(v1.x);
            acc[1] += bf_hi(v0.x) + bf_hi(v1.x);
            acc[2] += bf_lo(v0.y) + bf_lo(v1.y);
            acc[3] += bf_hi(v0.y) + bf_hi(v1.y);
            acc[4] += bf_lo(v0.z) + bf_lo(v1.z);
            acc[5] += bf_hi(v0.z) + bf_hi(v1.z);
            acc[6] += bf_lo(v0.w) + bf_lo(v1.w);
            acc[7] += bf_hi(v0.w) + bf_hi(v1.w);
        }
        {   // tail: 0..7 edges
            int i0 = base + sub;
            if (i0 < e) {
                int s0 = ssrc[i0];
                uint4 v0 = *(const uint4*)(feat + (size_t)s0 * NDIM + li * 8);
                acc[0] += bf_lo(v0.x); acc[1] += bf_hi(v0.x);
                acc[2] += bf_lo(v0.y); acc[3] += bf_hi(v0.y);
                acc[4] += bf_lo(v0.z); acc[5] += bf_hi(v0.z);
                acc[6] += bf_lo(v0.w); acc[7] += bf_hi(v0.w);
            }
            int i1 = base + 4 + sub;
            if (i1 < e) {
                int s1 = ssrc[i1];
                uint4 v1 = *(const uint4*)(feat + (size_t)s1 * NDIM + li * 8);
                acc[0] += bf_lo(v1.x); acc[1] += bf_hi(v1.x);
                acc[2] += bf_lo(v1.y); acc[3] += bf_hi(v1.y);
                acc[4] += bf_lo(v1.z); acc[5] += bf_hi(v1.z);
                acc[6] += bf_lo(v1.w); acc[7] += bf_hi(v1.w);
            }
        }

        // combine the 4 edge-slot partials (lane groups of 16)
#pragma unroll
        for (int k = 0; k < 8; ++k) {
            acc[k] += __shfl_xor(acc[k], 16, 64);
            acc[k] += __shfl_xor(acc[k], 32, 64);
        }

        if (sub == 0) {
            uint4 o;
            o.x = (uint32_t)f2bf(acc[0]) | ((uint32_t)f2bf(acc[1]) << 16);
            o.y = (uint32_t)f2bf(acc[2]) | ((uint32_t)f2bf(acc[3]) << 16);
            o.z = (uint32_t)f2bf(acc[4]) | ((uint32_t)f2bf(acc[5]) << 16);
            o.w = (uint32_t)f2bf(acc[6]) | ((uint32_t)f2bf(acc[7]) << 16);
            *(uint4*)(agg + (size_t)d * NDIM + li * 8) = o;
        }
    }
}

// fallback f32 agg into out (if workspace too small)
__global__ void k_agg_f32(const uint16_t* __restrict__ feat,
                          const float* __restrict__ h, const int* __restrict__ odeg,
                          const int* __restrict__ ssrc, const int* __restrict__ row_start,
                          float* __restrict__ agg, int ndst, int use_feat) {
    int gtid = blockIdx.x * blockDim.x + threadIdx.x;
    int wave = gtid >> 6;
    int lane = threadIdx.x & 63;
    int nwaves = (gridDim.x * blockDim.x) >> 6;
    for (int d = wave; d < ndst; d += nwaves) {
        int s = row_start[d], e = row_start[d + 1];
        float a0 = 0.f, a1 = 0.f;
        if (use_feat) {
            for (int i = s; i < e; i++) {
                uint32_t v0 = *(const uint32_t*)(feat + (size_t)ssrc[i] * NDIM + lane * 2);
                a0 += bf_lo(v0);
                a1 += bf_hi(v0);
            }
        } else {
            for (int i = s; i < e; i++) {
                int s0 = ssrc[i];
                float nrm = rsqrtf(fmaxf((float)odeg[s0], 1.0f));
                float2 v = ((const float2*)h)[(size_t)s0 * (NDIM / 2) + lane];
                a0 += v.x * nrm;
                a1 += v.y * nrm;
            }
        }
        float2 o; o.x = a0; o.y = a1;
        ((float2*)agg)[(size_t)d * (NDIM / 2) + lane] = o;
    }
}

// one-time: fragment W into MFMA B-layout (bf16).
// wfrag[((n*4+s)*64+lane)*8+i] = bf16(W[k][col]),  k=s*32+8*(lane>>4)+i, col=n*16+(lane&15)
__global__ void k_wfrag(const float* __restrict__ W, uint16_t* __restrict__ wfrag) {
    int t = blockIdx.x * blockDim.x + threadIdx.x;
    if (t >= NDIM * NDIM) return;
    int i    = t & 7;
    int lane = (t >> 3) & 63;
    int s    = (t >> 9) & 3;
    int n    = t >> 11;
    int k    = s * 32 + 8 * (lane >> 4) + i;
    int col  = n * 16 + (lane & 15);
    wfrag[t] = f2bf(W[k * NDIM + col]);
}

// MFMA GEMM: out[M][128] = (A_bf16[M][128] @ W) * rsqrt(clamp(ideg,1,K)) + bias
__global__ __launch_bounds__(256) void k_gemm_mfma(const uint16_t* __restrict__ A,
                                                   const uint16_t* __restrict__ wfrag,
                                                   const float* __restrict__ bias,
                                                   const int* __restrict__ ideg,
                                                   float* __restrict__ out, int M) {
    __shared__ uint16_t Ws[NDIM * NDIM];   // 32 KB, fragment layout
    int tx = threadIdx.x;
    for (int i = tx; i < NDIM * NDIM / 8; i += 256)
        ((int4*)Ws)[i] = ((const int4*)wfrag)[i];
    __syncthreads();

    int wave = tx >> 6, lane = tx & 63;
    int r0 = blockIdx.x * 64 + wave * 16;
    int arow = r0 + (lane & 15);
    if (arow >= M) arow = M - 1;            // clamp loads; stores predicated
    const bf16x8* Arow = (const bf16x8*)(A + (size_t)arow * NDIM);
    int g = lane >> 4;

    f32x4 acc[8];
#pragma unroll
    for (int n = 0; n < 8; ++n) acc[n] = (f32x4){0.f, 0.f, 0.f, 0.f};

#pragma unroll
    for (int s = 0; s < 4; ++s) {
        bf16x8 af = Arow[s * 4 + g];        // k = s*32 + 8g .. +7
#pragma unroll
        for (int n = 0; n < 8; ++n) {
            bf16x8 bfr = *(const bf16x8*)(Ws + (((n * 4 + s) * 64 + lane) << 3));
            acc[n] = __builtin_amdgcn_mfma_f32_16x16x32_bf16(af, bfr, acc[n], 0, 0, 0);
        }
    }

    int col = lane & 15;
    float nrm[4];
    int rowbase = r0 + g * 4;
#pragma unroll
    for (int r = 0; r < 4; ++r) {
        int row = rowbase + r;
        nrm[r] = (row < M) ? rsqrtf(fminf(fmaxf((float)ideg[row], 1.0f), KCLAMP)) : 0.f;
    }
#pragma unroll
    for (int n = 0; n < 8; ++n) {
        float b = bias[n * 16 + col];
#pragma unroll
        for (int r = 0; r < 4; ++r) {
            int row = rowbase + r;
            if (row < M)
                out[(size_t)row * NDIM + n * 16 + col] = acc[n][r] * nrm[r] + b;
        }
    }
}

// fallback f32 GEMM (in-place on out)
__global__ __launch_bounds__(256) void k_gemm_f32(float* __restrict__ io,
                                                  const float* __restrict__ W,
                                                  const float* __restrict__ bias,
                                                  const int* __restrict__ ideg, int M) {
    __shared__ float Wsf[NDIM][NDIM];
    int tx = threadIdx.x;
    {
        const float4* Wv = (const float4*)W;
        float4* Wsv = (float4*)&Wsf[0][0];
        for (int i = tx; i < NDIM * NDIM / 4; i += 256) Wsv[i] = Wv[i];
    }
    __syncthreads();
    int cg = tx & 31, rg = tx >> 5;
    int r0 = blockIdx.x * 64 + rg * 8, c0 = cg * 4;
    float acc[8][4];
#pragma unroll
    for (int r = 0; r < 8; ++r)
#pragma unroll
        for (int c = 0; c < 4; ++c) acc[r][c] = 0.f;
    for (int k4 = 0; k4 < NDIM / 4; ++k4) {
        float4 wk0 = *(const float4*)&Wsf[4 * k4 + 0][c0];
        float4 wk1 = *(const float4*)&Wsf[4 * k4 + 1][c0];
        float4 wk2 = *(const float4*)&Wsf[4 * k4 + 2][c0];
        float4 wk3 = *(const float4*)&Wsf[4 * k4 + 3][c0];
#pragma unroll
        for (int r = 0; r < 8; ++r) {
            int row = r0 + r;
            if (row < M) {
                float4 a = ((const float4*)io)[(size_t)row * (NDIM / 4) + k4];
                acc[r][0] += a.x * wk0.x + a.y * wk1.x + a.z * wk2.x + a.w * wk3.x;
                acc[r][1] += a.x * wk0.y + a.y * wk1.y + a.z * wk2.y + a.w * wk3.y;
                acc[r][2] += a.x * wk0.z + a.y * wk1.z + a.z * wk2.z + a.w * wk3.z;
                acc[r][3] += a.x * wk0.w + a.y * wk1.w + a.z * wk2.w + a.w * wk3.w;
            }
        }
    }
    __syncthreads();
    float4 b = *(const float4*)&bias[c0];
#pragma unroll
    for (int r = 0; r < 8; ++r) {
        int row = r0 + r;
        if (row < M) {
            float nrm = rsqrtf(fminf(fmaxf((float)ideg[row], 1.0f), KCLAMP));
            float4 o;
            o.x = acc[r][0] * nrm + b.x;
            o.y = acc[r][1] * nrm + b.y;
            o.z = acc[r][2] * nrm + b.z;
            o.w = acc[r][3] * nrm + b.w;
            ((float4*)io)[(size_t)row * (NDIM / 4) + cg] = o;
        }
    }
}

extern "C" void kernel_launch(void* const* d_in, const int* in_sizes, int n_in,
                              void* d_out, int out_size, void* d_ws, size_t ws_size,
                              hipStream_t stream) {
    const float* h_src  = (const float*)d_in[0];
    const float* weight = (const float*)d_in[1];
    const float* bias   = (const float*)d_in[2];
    const int*   ssrc   = (const int*)d_in[3];
    const int*   sdst   = (const int*)d_in[4];
    const int*   odeg   = (const int*)d_in[5];
    const int*   ideg   = (const int*)d_in[6];
    float* out = (float*)d_out;

    int E    = in_sizes[3];
    int nsrc = in_sizes[0] / NDIM;
    int ndst = out_size / NDIM;

    size_t featB = (size_t)nsrc * NDIM * 2;
    size_t aggB  = (size_t)ndst * NDIM * 2;

    // layout: [0,1MB) row_start ; [1MB, 1MB+32KB) wfrag ; [2MB, ..) feat ; then agg
    int*      row_start = (int*)d_ws;
    uint16_t* wfrag = (uint16_t*)((char*)d_ws + ((size_t)1 << 20));
    size_t feat_off = (size_t)2 << 20;
    uint16_t* feat  = (uint16_t*)((char*)d_ws + feat_off);
    size_t agg_off  = feat_off + ((featB + 255) & ~(size_t)255);
    uint16_t* aggbf = (uint16_t*)((char*)d_ws + agg_off);
    size_t need_full = agg_off + aggB;
    size_t need_feat = feat_off + featB;

    k_rowptr<<<(ndst + 1 + 255) / 256, 256, 0, stream>>>(sdst, E, row_start, ndst);

    if (ws_size >= need_full) {
        // fast path: bf16 agg + MFMA GEMM
        k_wfrag<<<(NDIM * NDIM + 255) / 256, 256, 0, stream>>>(weight, wfrag);
        int total = nsrc * (NDIM / 4);
        k_feat<<<(total + 255) / 256, 256, 0, stream>>>(h_src, odeg, feat, nsrc);
        k_agg_bf<<<2048, 256, 0, stream>>>(feat, ssrc, row_start, aggbf, ndst);
        k_gemm_mfma<<<(ndst + 63) / 64, 256, 0, stream>>>(aggbf, wfrag,
                                                          bias, ideg, out, ndst);
    } else {
        int use_feat = (ws_size >= need_feat) ? 1 : 0;
        if (use_feat) {
            int total = nsrc * (NDIM / 4);
            k_feat<<<(total + 255) / 256, 256, 0, stream>>>(h_src, odeg, feat, nsrc);
        }
        k_agg_f32<<<2048, 256, 0, stream>>>(feat, h_src, odeg, ssrc, row_start, out, ndst, use_feat);
        k_gemm_f32<<<(ndst + 63) / 64, 256, 0, stream>>>(out, weight, bias, ideg, ndst);
    }
}

// Round 4
// 86.539 us; speedup vs baseline: 2.9923x; 1.0292x over previous
//
#include <hip/hip_runtime.h>
#include <hip/hip_bf16.h>
#include <cstdint>

#define NDIM 128
#define KCLAMP 10.0f

using bf16x8 = __attribute__((ext_vector_type(8))) short;
using f32x4  = __attribute__((ext_vector_type(4))) float;
using f32x2  = __attribute__((ext_vector_type(2))) float;

__device__ __forceinline__ uint16_t f2bf(float f) {
    uint32_t u = __float_as_uint(f);
    uint32_t r = (u + 0x7fffu + ((u >> 16) & 1u)) >> 16;   // RNE
    return (uint16_t)r;
}
__device__ __forceinline__ float bf_lo(uint32_t v) { return __uint_as_float(v << 16); }
__device__ __forceinline__ float bf_hi(uint32_t v) { return __uint_as_float(v & 0xffff0000u); }

// feat[r][c] = h[r][c] * rsqrt(max(out_deg[r],1)), bf16
__global__ void k_feat(const float* __restrict__ h, const int* __restrict__ odeg,
                       uint16_t* __restrict__ feat, int nsrc) {
    int idx = blockIdx.x * blockDim.x + threadIdx.x;   // one float4 per thread
    int total = nsrc * (NDIM / 4);
    if (idx >= total) return;
    int row = idx >> 5;                                // NDIM/4 = 32
    float dg = (float)odeg[row];
    float nrm = rsqrtf(fmaxf(dg, 1.0f));
    float4 v = ((const float4*)h)[idx];
    ushort4 o;
    o.x = f2bf(v.x * nrm);
    o.y = f2bf(v.y * nrm);
    o.z = f2bf(v.z * nrm);
    o.w = f2bf(v.w * nrm);
    ((ushort4*)feat)[idx] = o;
}

// row_start[d] = lower_bound(sdst, d)
__global__ void k_rowptr(const int* __restrict__ sdst, int E,
                         int* __restrict__ row_start, int ndst) {
    int d = blockIdx.x * blockDim.x + threadIdx.x;
    if (d > ndst) return;
    int lo = 0, hi = E;
    while (lo < hi) {
        int mid = (lo + hi) >> 1;
        if (sdst[mid] < d) lo = mid + 1; else hi = mid;
    }
    row_start[d] = lo;
}

// 4 dst segments per wave (one per 16-lane slot), 8-deep load pipeline per slot.
// Row loads are unconditional with indices clamped to the segment's last edge
// (past-end steps re-load the same row -> L1 hits, no extra LLC traffic).
// Index loads for the next iteration are issued before the accumulates (SW pipeline).
__global__ void k_agg_bf(const uint16_t* __restrict__ feat,
                         const int* __restrict__ ssrc, const int* __restrict__ row_start,
                         uint16_t* __restrict__ agg, int ndst) {
    constexpr int U = 8;
    int gtid = blockIdx.x * blockDim.x + threadIdx.x;
    int wave = gtid >> 6;
    int lane = threadIdx.x & 63;
    int sub  = lane >> 4;          // dst slot 0..3
    int li   = lane & 15;          // 16B chunk within row
    int nwaves = (gridDim.x * blockDim.x) >> 6;

    for (int d0 = wave * 4; d0 < ndst; d0 += nwaves * 4) {
        int d = d0 + sub;
        int valid = (d < ndst);
        int s = 0, e = 0;
        if (valid) { s = row_start[d]; e = row_start[d + 1]; }
        int elast = (e > s) ? (e - 1) : 0;   // safe clamp index

        f32x2 acc[4];
#pragma unroll
        for (int k = 0; k < 4; ++k) acc[k] = (f32x2){0.f, 0.f};

        int idxv[U];
#pragma unroll
        for (int u = 0; u < U; ++u) idxv[u] = ssrc[min(s + u, elast)];

        int pos = s;
        while (__any(pos < e)) {
            uint4 v[U];
#pragma unroll
            for (int u = 0; u < U; ++u)
                v[u] = *(const uint4*)(feat + (size_t)idxv[u] * NDIM + li * 8);

            int npos = pos + U;
#pragma unroll
            for (int u = 0; u < U; ++u) idxv[u] = ssrc[min(npos + u, elast)];

#pragma unroll
            for (int u = 0; u < U; ++u) {
                if (pos + u < e) {
                    f32x2 t0 = {bf_lo(v[u].x), bf_hi(v[u].x)};
                    f32x2 t1 = {bf_lo(v[u].y), bf_hi(v[u].y)};
                    f32x2 t2 = {bf_lo(v[u].z), bf_hi(v[u].z)};
                    f32x2 t3 = {bf_lo(v[u].w), bf_hi(v[u].w)};
                    acc[0] += t0; acc[1] += t1; acc[2] += t2; acc[3] += t3;
                }
            }
            pos = npos;
        }

        if (valid) {
            uint4 o;
            o.x = (uint32_t)f2bf(acc[0][0]) | ((uint32_t)f2bf(acc[0][1]) << 16);
            o.y = (uint32_t)f2bf(acc[1][0]) | ((uint32_t)f2bf(acc[1][1]) << 16);
            o.z = (uint32_t)f2bf(acc[2][0]) | ((uint32_t)f2bf(acc[2][1]) << 16);
            o.w = (uint32_t)f2bf(acc[3][0]) | ((uint32_t)f2bf(acc[3][1]) << 16);
            *(uint4*)(agg + (size_t)d * NDIM + li * 8) = o;
        }
    }
}

// fallback f32 agg into out (if workspace too small)
__global__ void k_agg_f32(const uint16_t* __restrict__ feat,
                          const float* __restrict__ h, const int* __restrict__ odeg,
                          const int* __restrict__ ssrc, const int* __restrict__ row_start,
                          float* __restrict__ agg, int ndst, int use_feat) {
    int gtid = blockIdx.x * blockDim.x + threadIdx.x;
    int wave = gtid >> 6;
    int lane = threadIdx.x & 63;
    int nwaves = (gridDim.x * blockDim.x) >> 6;
    for (int d = wave; d < ndst; d += nwaves) {
        int s = row_start[d], e = row_start[d + 1];
        float a0 = 0.f, a1 = 0.f;
        if (use_feat) {
            for (int i = s; i < e; i++) {
                uint32_t v0 = *(const uint32_t*)(feat + (size_t)ssrc[i] * NDIM + lane * 2);
                a0 += bf_lo(v0);
                a1 += bf_hi(v0);
            }
        } else {
            for (int i = s; i < e; i++) {
                int s0 = ssrc[i];
                float nrm = rsqrtf(fmaxf((float)odeg[s0], 1.0f));
                float2 v = ((const float2*)h)[(size_t)s0 * (NDIM / 2) + lane];
                a0 += v.x * nrm;
                a1 += v.y * nrm;
            }
        }
        float2 o; o.x = a0; o.y = a1;
        ((float2*)agg)[(size_t)d * (NDIM / 2) + lane] = o;
    }
}

// one-time: fragment W into MFMA B-layout (bf16).
// wfrag[((n*4+s)*64+lane)*8+i] = bf16(W[k][col]),  k=s*32+8*(lane>>4)+i, col=n*16+(lane&15)
__global__ void k_wfrag(const float* __restrict__ W, uint16_t* __restrict__ wfrag) {
    int t = blockIdx.x * blockDim.x + threadIdx.x;
    if (t >= NDIM * NDIM) return;
    int i    = t & 7;
    int lane = (t >> 3) & 63;
    int s    = (t >> 9) & 3;
    int n    = t >> 11;
    int k    = s * 32 + 8 * (lane >> 4) + i;
    int col  = n * 16 + (lane & 15);
    wfrag[t] = f2bf(W[k * NDIM + col]);
}

// MFMA GEMM: out[M][128] = (A_bf16[M][128] @ W) * rsqrt(clamp(ideg,1,K)) + bias
__global__ __launch_bounds__(256) void k_gemm_mfma(const uint16_t* __restrict__ A,
                                                   const uint16_t* __restrict__ wfrag,
                                                   const float* __restrict__ bias,
                                                   const int* __restrict__ ideg,
                                                   float* __restrict__ out, int M) {
    __shared__ uint16_t Ws[NDIM * NDIM];   // 32 KB, fragment layout
    int tx = threadIdx.x;
    for (int i = tx; i < NDIM * NDIM / 8; i += 256)
        ((int4*)Ws)[i] = ((const int4*)wfrag)[i];
    __syncthreads();

    int wave = tx >> 6, lane = tx & 63;
    int r0 = blockIdx.x * 64 + wave * 16;
    int arow = r0 + (lane & 15);
    if (arow >= M) arow = M - 1;            // clamp loads; stores predicated
    const bf16x8* Arow = (const bf16x8*)(A + (size_t)arow * NDIM);
    int g = lane >> 4;

    f32x4 acc[8];
#pragma unroll
    for (int n = 0; n < 8; ++n) acc[n] = (f32x4){0.f, 0.f, 0.f, 0.f};

#pragma unroll
    for (int s = 0; s < 4; ++s) {
        bf16x8 af = Arow[s * 4 + g];        // k = s*32 + 8g .. +7
#pragma unroll
        for (int n = 0; n < 8; ++n) {
            bf16x8 bfr = *(const bf16x8*)(Ws + (((n * 4 + s) * 64 + lane) << 3));
            acc[n] = __builtin_amdgcn_mfma_f32_16x16x32_bf16(af, bfr, acc[n], 0, 0, 0);
        }
    }

    int col = lane & 15;
    float nrm[4];
    int rowbase = r0 + g * 4;
#pragma unroll
    for (int r = 0; r < 4; ++r) {
        int row = rowbase + r;
        nrm[r] = (row < M) ? rsqrtf(fminf(fmaxf((float)ideg[row], 1.0f), KCLAMP)) : 0.f;
    }
#pragma unroll
    for (int n = 0; n < 8; ++n) {
        float b = bias[n * 16 + col];
#pragma unroll
        for (int r = 0; r < 4; ++r) {
            int row = rowbase + r;
            if (row < M)
                out[(size_t)row * NDIM + n * 16 + col] = acc[n][r] * nrm[r] + b;
        }
    }
}

// fallback f32 GEMM (in-place on out)
__global__ __launch_bounds__(256) void k_gemm_f32(float* __restrict__ io,
                                                  const float* __restrict__ W,
                                                  const float* __restrict__ bias,
                                                  const int* __restrict__ ideg, int M) {
    __shared__ float Wsf[NDIM][NDIM];
    int tx = threadIdx.x;
    {
        const float4* Wv = (const float4*)W;
        float4* Wsv = (float4*)&Wsf[0][0];
        for (int i = tx; i < NDIM * NDIM / 4; i += 256) Wsv[i] = Wv[i];
    }
    __syncthreads();
    int cg = tx & 31, rg = tx >> 5;
    int r0 = blockIdx.x * 64 + rg * 8, c0 = cg * 4;
    float acc[8][4];
#pragma unroll
    for (int r = 0; r < 8; ++r)
#pragma unroll
        for (int c = 0; c < 4; ++c) acc[r][c] = 0.f;
    for (int k4 = 0; k4 < NDIM / 4; ++k4) {
        float4 wk0 = *(const float4*)&Wsf[4 * k4 + 0][c0];
        float4 wk1 = *(const float4*)&Wsf[4 * k4 + 1][c0];
        float4 wk2 = *(const float4*)&Wsf[4 * k4 + 2][c0];
        float4 wk3 = *(const float4*)&Wsf[4 * k4 + 3][c0];
#pragma unroll
        for (int r = 0; r < 8; ++r) {
            int row = r0 + r;
            if (row < M) {
                float4 a = ((const float4*)io)[(size_t)row * (NDIM / 4) + k4];
                acc[r][0] += a.x * wk0.x + a.y * wk1.x + a.z * wk2.x + a.w * wk3.x;
                acc[r][1] += a.x * wk0.y + a.y * wk1.y + a.z * wk2.y + a.w * wk3.y;
                acc[r][2] += a.x * wk0.z + a.y * wk1.z + a.z * wk2.z + a.w * wk3.z;
                acc[r][3] += a.x * wk0.w + a.y * wk1.w + a.z * wk2.w + a.w * wk3.w;
            }
        }
    }
    __syncthreads();
    float4 b = *(const float4*)&bias[c0];
#pragma unroll
    for (int r = 0; r < 8; ++r) {
        int row = r0 + r;
        if (row < M) {
            float nrm = rsqrtf(fminf(fmaxf((float)ideg[row], 1.0f), KCLAMP));
            float4 o;
            o.x = acc[r][0] * nrm + b.x;
            o.y = acc[r][1] * nrm + b.y;
            o.z = acc[r][2] * nrm + b.z;
            o.w = acc[r][3] * nrm + b.w;
            ((float4*)io)[(size_t)row * (NDIM / 4) + cg] = o;
        }
    }
}

extern "C" void kernel_launch(void* const* d_in, const int* in_sizes, int n_in,
                              void* d_out, int out_size, void* d_ws, size_t ws_size,
                              hipStream_t stream) {
    const float* h_src  = (const float*)d_in[0];
    const float* weight = (const float*)d_in[1];
    const float* bias   = (const float*)d_in[2];
    const int*   ssrc   = (const int*)d_in[3];
    const int*   sdst   = (const int*)d_in[4];
    const int*   odeg   = (const int*)d_in[5];
    const int*   ideg   = (const int*)d_in[6];
    float* out = (float*)d_out;

    int E    = in_sizes[3];
    int nsrc = in_sizes[0] / NDIM;
    int ndst = out_size / NDIM;

    size_t featB = (size_t)nsrc * NDIM * 2;
    size_t aggB  = (size_t)ndst * NDIM * 2;

    // layout: [0,1MB) row_start ; [1MB, 1MB+32KB) wfrag ; [2MB, ..) feat ; then agg
    int*      row_start = (int*)d_ws;
    uint16_t* wfrag = (uint16_t*)((char*)d_ws + ((size_t)1 << 20));
    size_t feat_off = (size_t)2 << 20;
    uint16_t* feat  = (uint16_t*)((char*)d_ws + feat_off);
    size_t agg_off  = feat_off + ((featB + 255) & ~(size_t)255);
    uint16_t* aggbf = (uint16_t*)((char*)d_ws + agg_off);
    size_t need_full = agg_off + aggB;
    size_t need_feat = feat_off + featB;

    k_rowptr<<<(ndst + 1 + 255) / 256, 256, 0, stream>>>(sdst, E, row_start, ndst);

    if (ws_size >= need_full) {
        // fast path: bf16 agg + MFMA GEMM
        k_wfrag<<<(NDIM * NDIM + 255) / 256, 256, 0, stream>>>(weight, wfrag);
        int total = nsrc * (NDIM / 4);
        k_feat<<<(total + 255) / 256, 256, 0, stream>>>(h_src, odeg, feat, nsrc);
        k_agg_bf<<<2048, 256, 0, stream>>>(feat, ssrc, row_start, aggbf, ndst);
        k_gemm_mfma<<<(ndst + 63) / 64, 256, 0, stream>>>(aggbf, wfrag,
                                                          bias, ideg, out, ndst);
    } else {
        int use_feat = (ws_size >= need_feat) ? 1 : 0;
        if (use_feat) {
            int total = nsrc * (NDIM / 4);
            k_feat<<<(total + 255) / 256, 256, 0, stream>>>(h_src, odeg, feat, nsrc);
        }
        k_agg_f32<<<2048, 256, 0, stream>>>(feat, h_src, odeg, ssrc, row_start, out, ndst, use_feat);
        k_gemm_f32<<<(ndst + 63) / 64, 256, 0, stream>>>(out, weight, bias, ideg, ndst);
    }
}

// Round 5
// 83.419 us; speedup vs baseline: 3.1042x; 1.0374x over previous
//
#include <hip/hip_runtime.h>
#include <hip/hip_bf16.h>
#include <cstdint>

#define NDIM 128
#define KCLAMP 10.0f
#define BLK_D 128

using bf16x8 = __attribute__((ext_vector_type(8))) short;
using f32x4  = __attribute__((ext_vector_type(4))) float;
using f32x2  = __attribute__((ext_vector_type(2))) float;

__device__ __forceinline__ uint16_t f2bf(float f) {
    uint32_t u = __float_as_uint(f);
    uint32_t r = (u + 0x7fffu + ((u >> 16) & 1u)) >> 16;   // RNE
    return (uint16_t)r;
}
__device__ __forceinline__ float bf_lo(uint32_t v) { return __uint_as_float(v << 16); }
__device__ __forceinline__ float bf_hi(uint32_t v) { return __uint_as_float(v & 0xffff0000u); }

// ---------- prep: feat + rowptr + wfrag in one launch (role by blockIdx) ----------
__global__ void k_prep(const float* __restrict__ h, const int* __restrict__ odeg,
                       uint16_t* __restrict__ feat, int nsrc,
                       const int* __restrict__ sdst, int E,
                       int* __restrict__ row_start, int ndst,
                       const float* __restrict__ W, uint16_t* __restrict__ wfrag,
                       int featBlocks, int rpBlocks) {
    int b = blockIdx.x;
    int tid = threadIdx.x;
    if (b < featBlocks) {
        int idx = b * 256 + tid;                  // one float4 per thread
        int total = nsrc * (NDIM / 4);
        if (idx >= total) return;
        int row = idx >> 5;
        float nrm = rsqrtf(fmaxf((float)odeg[row], 1.0f));
        float4 v = ((const float4*)h)[idx];
        ushort4 o;
        o.x = f2bf(v.x * nrm);
        o.y = f2bf(v.y * nrm);
        o.z = f2bf(v.z * nrm);
        o.w = f2bf(v.w * nrm);
        ((ushort4*)feat)[idx] = o;
    } else if (b < featBlocks + rpBlocks) {
        int d = (b - featBlocks) * 256 + tid;     // lower_bound(sdst, d)
        if (d > ndst) return;
        int lo = 0, hi = E;
        while (lo < hi) {
            int mid = (lo + hi) >> 1;
            if (sdst[mid] < d) lo = mid + 1; else hi = mid;
        }
        row_start[d] = lo;
    } else {
        int t = (b - featBlocks - rpBlocks) * 256 + tid;   // W -> MFMA B-frag layout
        if (t >= NDIM * NDIM) return;
        int i    = t & 7;
        int lane = (t >> 3) & 63;
        int s    = (t >> 9) & 3;
        int n    = t >> 11;
        int k    = s * 32 + 8 * (lane >> 4) + i;
        int col  = n * 16 + (lane & 15);
        wfrag[t] = f2bf(W[k * NDIM + col]);
    }
}

// ---------- fused agg + MFMA GEMM ----------
// Block: 512 threads = 8 waves, 128 dsts. Phase A: 32 slots (wave*4+sub) each
// aggregate 4 consecutive dsts (8-deep clamped load pipeline per slot), writing
// bf16 rows into a XOR-swizzled LDS A-tile. Phase B: wave w MFMAs rows w*16..+15
// against W (staged in LDS at kernel entry, hidden under phase A), fused epilogue.
__global__ __launch_bounds__(512) void k_fused(const uint16_t* __restrict__ feat,
                                               const int* __restrict__ ssrc,
                                               const int* __restrict__ row_start,
                                               const uint16_t* __restrict__ wfrag,
                                               const float* __restrict__ bias,
                                               const int* __restrict__ ideg,
                                               float* __restrict__ out, int ndst) {
    constexpr int U = 8;
    __shared__ uint16_t Ws[NDIM * NDIM];      // 32 KB, B-frag layout
    __shared__ uint16_t Asm[BLK_D * NDIM];    // 32 KB, swizzled bf16 A-tile

    int tx = threadIdx.x;
    // stage W fragments (completion enforced by the phase-A/B barrier)
    for (int i = tx; i < NDIM * NDIM / 8; i += 512)
        ((int4*)Ws)[i] = ((const int4*)wfrag)[i];

    int wave = tx >> 6, lane = tx & 63;
    int sub  = lane >> 4;            // slot within wave (0..3)
    int li   = lane & 15;            // 16B chunk within row
    int sid  = wave * 4 + sub;       // 0..31
    int base = blockIdx.x * BLK_D;

    // ---- phase A: aggregate 4 dsts per slot ----
    for (int j = 0; j < 4; ++j) {
        int r = sid * 4 + j;         // local row 0..127
        int d = base + r;
        int valid = (d < ndst);
        int s = 0, e = 0;
        if (valid) { s = row_start[d]; e = row_start[d + 1]; }
        int elast = (e > s) ? (e - 1) : 0;

        f32x2 acc[4];
#pragma unroll
        for (int k = 0; k < 4; ++k) acc[k] = (f32x2){0.f, 0.f};

        int idxv[U];
#pragma unroll
        for (int u = 0; u < U; ++u) idxv[u] = ssrc[min(s + u, elast)];

        int pos = s;
        while (__any(pos < e)) {
            uint4 v[U];
#pragma unroll
            for (int u = 0; u < U; ++u)
                v[u] = *(const uint4*)(feat + (size_t)idxv[u] * NDIM + li * 8);

            int npos = pos + U;
#pragma unroll
            for (int u = 0; u < U; ++u) idxv[u] = ssrc[min(npos + u, elast)];

#pragma unroll
            for (int u = 0; u < U; ++u) {
                if (pos + u < e) {
                    f32x2 t0 = {bf_lo(v[u].x), bf_hi(v[u].x)};
                    f32x2 t1 = {bf_lo(v[u].y), bf_hi(v[u].y)};
                    f32x2 t2 = {bf_lo(v[u].z), bf_hi(v[u].z)};
                    f32x2 t3 = {bf_lo(v[u].w), bf_hi(v[u].w)};
                    acc[0] += t0; acc[1] += t1; acc[2] += t2; acc[3] += t3;
                }
            }
            pos = npos;
        }

        uint4 o;
        o.x = (uint32_t)f2bf(acc[0][0]) | ((uint32_t)f2bf(acc[0][1]) << 16);
        o.y = (uint32_t)f2bf(acc[1][0]) | ((uint32_t)f2bf(acc[1][1]) << 16);
        o.z = (uint32_t)f2bf(acc[2][0]) | ((uint32_t)f2bf(acc[2][1]) << 16);
        o.w = (uint32_t)f2bf(acc[3][0]) | ((uint32_t)f2bf(acc[3][1]) << 16);
        int byte = (r * 256 + li * 16) ^ ((r & 7) << 4);   // XOR swizzle (G4)
        *(uint4*)((char*)Asm + byte) = o;
    }

    __syncthreads();

    // ---- phase B: MFMA rows wave*16..+15 ----
    int g = lane >> 4;
    int rloc = wave * 16 + (lane & 15);

    f32x4 acc[8];
#pragma unroll
    for (int n = 0; n < 8; ++n) acc[n] = (f32x4){0.f, 0.f, 0.f, 0.f};

#pragma unroll
    for (int s = 0; s < 4; ++s) {
        int abyte = (rloc * 256 + s * 64 + g * 16) ^ ((rloc & 7) << 4);
        bf16x8 af = *(const bf16x8*)((const char*)Asm + abyte);
#pragma unroll
        for (int n = 0; n < 8; ++n) {
            bf16x8 bfr = *(const bf16x8*)(Ws + (((n * 4 + s) * 64 + lane) << 3));
            acc[n] = __builtin_amdgcn_mfma_f32_16x16x32_bf16(af, bfr, acc[n], 0, 0, 0);
        }
    }

    int col = lane & 15;
    int rowbase = base + wave * 16 + g * 4;
    float nrm[4];
#pragma unroll
    for (int r = 0; r < 4; ++r) {
        int row = rowbase + r;
        nrm[r] = (row < ndst) ? rsqrtf(fminf(fmaxf((float)ideg[row], 1.0f), KCLAMP)) : 0.f;
    }
#pragma unroll
    for (int n = 0; n < 8; ++n) {
        float b = bias[n * 16 + col];
#pragma unroll
        for (int r = 0; r < 4; ++r) {
            int row = rowbase + r;
            if (row < ndst)
                out[(size_t)row * NDIM + n * 16 + col] = acc[n][r] * nrm[r] + b;
        }
    }
}

// ---------- fallbacks (workspace too small) ----------
__global__ void k_rowptr(const int* __restrict__ sdst, int E,
                         int* __restrict__ row_start, int ndst) {
    int d = blockIdx.x * blockDim.x + threadIdx.x;
    if (d > ndst) return;
    int lo = 0, hi = E;
    while (lo < hi) {
        int mid = (lo + hi) >> 1;
        if (sdst[mid] < d) lo = mid + 1; else hi = mid;
    }
    row_start[d] = lo;
}

__global__ void k_feat(const float* __restrict__ h, const int* __restrict__ odeg,
                       uint16_t* __restrict__ feat, int nsrc) {
    int idx = blockIdx.x * blockDim.x + threadIdx.x;
    int total = nsrc * (NDIM / 4);
    if (idx >= total) return;
    int row = idx >> 5;
    float nrm = rsqrtf(fmaxf((float)odeg[row], 1.0f));
    float4 v = ((const float4*)h)[idx];
    ushort4 o;
    o.x = f2bf(v.x * nrm);
    o.y = f2bf(v.y * nrm);
    o.z = f2bf(v.z * nrm);
    o.w = f2bf(v.w * nrm);
    ((ushort4*)feat)[idx] = o;
}

__global__ void k_agg_f32(const uint16_t* __restrict__ feat,
                          const float* __restrict__ h, const int* __restrict__ odeg,
                          const int* __restrict__ ssrc, const int* __restrict__ row_start,
                          float* __restrict__ agg, int ndst, int use_feat) {
    int gtid = blockIdx.x * blockDim.x + threadIdx.x;
    int wave = gtid >> 6;
    int lane = threadIdx.x & 63;
    int nwaves = (gridDim.x * blockDim.x) >> 6;
    for (int d = wave; d < ndst; d += nwaves) {
        int s = row_start[d], e = row_start[d + 1];
        float a0 = 0.f, a1 = 0.f;
        if (use_feat) {
            for (int i = s; i < e; i++) {
                uint32_t v0 = *(const uint32_t*)(feat + (size_t)ssrc[i] * NDIM + lane * 2);
                a0 += bf_lo(v0);
                a1 += bf_hi(v0);
            }
        } else {
            for (int i = s; i < e; i++) {
                int s0 = ssrc[i];
                float nrm = rsqrtf(fmaxf((float)odeg[s0], 1.0f));
                float2 v = ((const float2*)h)[(size_t)s0 * (NDIM / 2) + lane];
                a0 += v.x * nrm;
                a1 += v.y * nrm;
            }
        }
        float2 o; o.x = a0; o.y = a1;
        ((float2*)agg)[(size_t)d * (NDIM / 2) + lane] = o;
    }
}

__global__ __launch_bounds__(256) void k_gemm_f32(float* __restrict__ io,
                                                  const float* __restrict__ W,
                                                  const float* __restrict__ bias,
                                                  const int* __restrict__ ideg, int M) {
    __shared__ float Wsf[NDIM][NDIM];
    int tx = threadIdx.x;
    {
        const float4* Wv = (const float4*)W;
        float4* Wsv = (float4*)&Wsf[0][0];
        for (int i = tx; i < NDIM * NDIM / 4; i += 256) Wsv[i] = Wv[i];
    }
    __syncthreads();
    int cg = tx & 31, rg = tx >> 5;
    int r0 = blockIdx.x * 64 + rg * 8, c0 = cg * 4;
    float acc[8][4];
#pragma unroll
    for (int r = 0; r < 8; ++r)
#pragma unroll
        for (int c = 0; c < 4; ++c) acc[r][c] = 0.f;
    for (int k4 = 0; k4 < NDIM / 4; ++k4) {
        float4 wk0 = *(const float4*)&Wsf[4 * k4 + 0][c0];
        float4 wk1 = *(const float4*)&Wsf[4 * k4 + 1][c0];
        float4 wk2 = *(const float4*)&Wsf[4 * k4 + 2][c0];
        float4 wk3 = *(const float4*)&Wsf[4 * k4 + 3][c0];
#pragma unroll
        for (int r = 0; r < 8; ++r) {
            int row = r0 + r;
            if (row < M) {
                float4 a = ((const float4*)io)[(size_t)row * (NDIM / 4) + k4];
                acc[r][0] += a.x * wk0.x + a.y * wk1.x + a.z * wk2.x + a.w * wk3.x;
                acc[r][1] += a.x * wk0.y + a.y * wk1.y + a.z * wk2.y + a.w * wk3.y;
                acc[r][2] += a.x * wk0.z + a.y * wk1.z + a.z * wk2.z + a.w * wk3.z;
                acc[r][3] += a.x * wk0.w + a.y * wk1.w + a.z * wk2.w + a.w * wk3.w;
            }
        }
    }
    __syncthreads();
    float4 b = *(const float4*)&bias[c0];
#pragma unroll
    for (int r = 0; r < 8; ++r) {
        int row = r0 + r;
        if (row < M) {
            float nrm = rsqrtf(fminf(fmaxf((float)ideg[row], 1.0f), KCLAMP));
            float4 o;
            o.x = acc[r][0] * nrm + b.x;
            o.y = acc[r][1] * nrm + b.y;
            o.z = acc[r][2] * nrm + b.z;
            o.w = acc[r][3] * nrm + b.w;
            ((float4*)io)[(size_t)row * (NDIM / 4) + cg] = o;
        }
    }
}

extern "C" void kernel_launch(void* const* d_in, const int* in_sizes, int n_in,
                              void* d_out, int out_size, void* d_ws, size_t ws_size,
                              hipStream_t stream) {
    const float* h_src  = (const float*)d_in[0];
    const float* weight = (const float*)d_in[1];
    const float* bias   = (const float*)d_in[2];
    const int*   ssrc   = (const int*)d_in[3];
    const int*   sdst   = (const int*)d_in[4];
    const int*   odeg   = (const int*)d_in[5];
    const int*   ideg   = (const int*)d_in[6];
    float* out = (float*)d_out;

    int E    = in_sizes[3];
    int nsrc = in_sizes[0] / NDIM;
    int ndst = out_size / NDIM;

    size_t featB = (size_t)nsrc * NDIM * 2;

    // layout: [0,1MB) row_start ; [1MB,1MB+32KB) wfrag ; [2MB,..) feat
    int*      row_start = (int*)d_ws;
    uint16_t* wfrag = (uint16_t*)((char*)d_ws + ((size_t)1 << 20));
    size_t feat_off = (size_t)2 << 20;
    uint16_t* feat  = (uint16_t*)((char*)d_ws + feat_off);
    size_t need = feat_off + featB;

    if (ws_size >= need) {
        int featBlocks = (nsrc * (NDIM / 4) + 255) / 256;
        int rpBlocks   = (ndst + 1 + 255) / 256;
        int wfBlocks   = (NDIM * NDIM + 255) / 256;
        k_prep<<<featBlocks + rpBlocks + wfBlocks, 256, 0, stream>>>(
            h_src, odeg, feat, nsrc, sdst, E, row_start, ndst,
            weight, wfrag, featBlocks, rpBlocks);
        k_fused<<<(ndst + BLK_D - 1) / BLK_D, 512, 0, stream>>>(
            feat, ssrc, row_start, wfrag, bias, ideg, out, ndst);
    } else {
        k_rowptr<<<(ndst + 1 + 255) / 256, 256, 0, stream>>>(sdst, E, row_start, ndst);
        k_agg_f32<<<2048, 256, 0, stream>>>(feat, h_src, odeg, ssrc, row_start, out, ndst, 0);
        k_gemm_f32<<<(ndst + 63) / 64, 256, 0, stream>>>(out, weight, bias, ideg, ndst);
    }
}